// Round 4
// baseline (220.680 us; speedup 1.0000x reference)
//
#include <hip/hip_runtime.h>

using half8   = __attribute__((ext_vector_type(8))) _Float16;
using f32x4   = __attribute__((ext_vector_type(4))) float;
using ushort8 = __attribute__((ext_vector_type(8))) unsigned short;

__device__ __forceinline__ void gload16(const void* g, void* l) {
  __builtin_amdgcn_global_load_lds(
      (const __attribute__((address_space(1))) void*)g,
      (__attribute__((address_space(3))) void*)l, 16, 0, 0);
}

// ---------------- cast fp32 -> fp16 ----------------
__global__ __launch_bounds__(256) void cast_f32_f16(
    const float* __restrict__ in, unsigned short* __restrict__ out, long n) {
  long i = ((long)blockIdx.x * 256 + threadIdx.x) * 8;
  if (i >= n) return;
  float4 a = *(const float4*)(in + i);
  float4 b = *(const float4*)(in + i + 4);
  union { _Float16 h[8]; ushort8 u; } r;
  r.h[0] = (_Float16)a.x; r.h[1] = (_Float16)a.y;
  r.h[2] = (_Float16)a.z; r.h[3] = (_Float16)a.w;
  r.h[4] = (_Float16)b.x; r.h[5] = (_Float16)b.y;
  r.h[6] = (_Float16)b.z; r.h[7] = (_Float16)b.w;
  *(ushort8*)(out + i) = r.u;
}

// ============ 8-wave single-barrier-region NT GEMM: C = A[M,K]*B[N,K]^T ============
// BM=256, BN=64*N_REP, BK=64, 512 threads (2Mx4N waves), per-wave 128 x 16*N_REP.
// Region (t,p) = { s_barrier; lgkmcnt(0); 4*N_REP MFMA on frags read LAST region;
//                  stage-issues; ds_reads for NEXT region; [fence] }.
// Reads overlap the MFMA pipe drain (MFMA doesn't block the wave).
// Staging: A(t+1)[4 loads] at p0 -> A slot^1; B(t+2)[N_REP] at p1 -> B slot cur
// (dead: its frags were consumed from regs since (t-1,p3)). Producer fence
// vmcnt(N_REP) at END of p2, BEFORE the p3 barrier after which other waves read
// the staged A(t+1)/B(t+1) -> cross-wave safe, and never drains to 0 in steady
// state (T4). B-frags double-buffered in regs; tile loop unrolled x2 so all
// frag-array indices are compile-time (no scratch).
#define FENCE_N()                                                                  \
  do {                                                                             \
    if constexpr (N_REP == 2)      asm volatile("s_waitcnt vmcnt(2)" ::: "memory");\
    else if constexpr (N_REP == 3) asm volatile("s_waitcnt vmcnt(3)" ::: "memory");\
    else                           asm volatile("s_waitcnt vmcnt(4)" ::: "memory");\
  } while (0)

#define PHASE(P, AC, AN, BC, BNX)                                                  \
  {                                                                                \
    __builtin_amdgcn_s_barrier();                                                  \
    asm volatile("s_waitcnt lgkmcnt(0)" ::: "memory");                             \
    __builtin_amdgcn_sched_barrier(0);                                             \
    __builtin_amdgcn_s_setprio(1);                                                 \
    _Pragma("unroll") for (int ks = 0; ks < 2; ++ks)                               \
    _Pragma("unroll") for (int i = 0; i < 2; ++i)                                  \
    _Pragma("unroll") for (int ni = 0; ni < N_REP; ++ni)                           \
      acc[2 * (P) + i][ni] = __builtin_amdgcn_mfma_f32_16x16x32_f16(               \
          AC[i][ks], BC[ni][ks], acc[2 * (P) + i][ni], 0, 0, 0);                   \
    __builtin_amdgcn_s_setprio(0);                                                 \
    __builtin_amdgcn_sched_barrier(0);                                             \
    if ((P) == 0 && t + 1 < nt) {                                                  \
      unsigned short* d = ldsA + (SLOT ^ 1) * ASZ + wv * 512;                      \
      const long kt = (long)(t + 1) * 64;                                          \
      gload16(aS + kt, d);                                                         \
      gload16(aS + (long)64 * lda + kt, d + 4096);                                 \
      gload16(aS + (long)128 * lda + kt, d + 8192);                                \
      gload16(aS + (long)192 * lda + kt, d + 12288);                               \
    }                                                                              \
    if ((P) == 1 && t + 2 < nt) {                                                  \
      const long kt = (long)(t + 2) * 64;                                          \
      _Pragma("unroll") for (int j = 0; j < N_REP; ++j)                            \
        gload16(bS + (long)(j * 64) * ldb + kt,                                    \
                ldsB + SLOT * BSZ + j * 4096 + wv * 512);                          \
    }                                                                              \
    if ((P) < 3) {                                                                 \
      _Pragma("unroll") for (int i = 0; i < 2; ++i) {                              \
        AN[i][0] = *(const half8*)(lA + aRd + (2 * ((P) + 1) + i) * 2048 + kg0);   \
        AN[i][1] = *(const half8*)(lA + aRd + (2 * ((P) + 1) + i) * 2048 + kg1);   \
      }                                                                            \
    } else if (t + 1 < nt) {                                                       \
      _Pragma("unroll") for (int i = 0; i < 2; ++i) {                              \
        AN[i][0] = *(const half8*)(lAo + aRd + i * 2048 + kg0);                    \
        AN[i][1] = *(const half8*)(lAo + aRd + i * 2048 + kg1);                    \
      }                                                                            \
      _Pragma("unroll") for (int ni = 0; ni < N_REP; ++ni) {                       \
        BNX[ni][0] = *(const half8*)(lBo + bRd + ni * 2048 + kg0);                 \
        BNX[ni][1] = *(const half8*)(lBo + bRd + ni * 2048 + kg1);                 \
      }                                                                            \
    }                                                                              \
    if ((P) == 2) {                                                                \
      if (t + 2 < nt) FENCE_N();                                                   \
      else asm volatile("s_waitcnt vmcnt(0)" ::: "memory");                        \
    }                                                                              \
    __builtin_amdgcn_sched_barrier(0);                                             \
  }

#define TILE(T, S, BCARR, BNARR)                                                   \
  {                                                                                \
    const int t = (T);                                                             \
    constexpr int SLOT = (S);                                                      \
    const char* lA  = (const char*)(ldsA + SLOT * ASZ);                            \
    const char* lAo = (const char*)(ldsA + (SLOT ^ 1) * ASZ);                      \
    const char* lBo = (const char*)(ldsB + (SLOT ^ 1) * BSZ);                      \
    PHASE(0, afE, afO, BCARR, BNARR)                                               \
    PHASE(1, afO, afE, BCARR, BNARR)                                               \
    PHASE(2, afE, afO, BCARR, BNARR)                                               \
    PHASE(3, afO, afE, BCARR, BNARR)                                               \
  }

template <int MODE, int N_REP>
__global__ __launch_bounds__(512, 2) void gemm8p(
    const unsigned short* __restrict__ Ab, const unsigned short* __restrict__ Bb,
    int K, int lda, int ldb, long sA, long sB,
    void* __restrict__ o0, void* __restrict__ o1, void* __restrict__ o2) {
  constexpr int BM  = 256;
  constexpr int BN  = 64 * N_REP;
  constexpr int ASZ = BM * 64;
  constexpr int BSZ = BN * 64;
  __shared__ unsigned short lds[2 * ASZ + 2 * BSZ];

  const int tid  = threadIdx.x;
  const int lane = tid & 63;
  const int wv   = tid >> 6;
  const int wr   = wv >> 2, wc = wv & 3;
  const int fr   = lane & 15, fq = lane >> 4;
  const int bm   = blockIdx.y * BM;
  const int bn   = blockIdx.x * BN;
  const int bz   = blockIdx.z;

  const unsigned short* A = Ab + (long)bz * sA;
  const unsigned short* B = Bb + (long)bz * sB;

  // staging map: thread t -> row tid>>3 in a 64-row unit, 16B granule tid&7,
  // source pre-swizzled (gload_lds writes linearly; reads apply same XOR)
  const int row_s = tid >> 3;
  const int col_s = ((tid & 7) ^ (row_s & 7)) * 8;
  const unsigned short* aS = A + (long)(bm + row_s) * lda + col_s;
  const unsigned short* bS = B + (long)(bn + row_s) * ldb + col_s;
  unsigned short* ldsA = lds;
  unsigned short* ldsB = lds + 2 * ASZ;

  const int kg0 = ((0 * 4 + fq) ^ (fr & 7)) * 16;
  const int kg1 = ((1 * 4 + fq) ^ (fr & 7)) * 16;
  const int aRd = (wr * 128 + fr) * 128;
  const int bRd = (wc * (16 * N_REP) + fr) * 128;

  f32x4 acc[8][N_REP] = {};
  half8 afE[2][2], afO[2][2];
  half8 bf0[N_REP][2], bf1[N_REP][2];

  const int nt = K / 64;

  // ---- prologue: stage A(0),B(0); drain; read (0,p0) frags; issue B(1) ----
#pragma unroll
  for (int i = 0; i < 4; ++i)
    gload16(aS + (long)(i * 64) * lda, ldsA + i * 4096 + wv * 512);
#pragma unroll
  for (int j = 0; j < N_REP; ++j)
    gload16(bS + (long)(j * 64) * ldb, ldsB + j * 4096 + wv * 512);
  asm volatile("s_waitcnt vmcnt(0)" ::: "memory");
  __builtin_amdgcn_s_barrier();
  {
    const char* lA0 = (const char*)ldsA;
    const char* lB0 = (const char*)ldsB;
#pragma unroll
    for (int i = 0; i < 2; ++i) {
      afE[i][0] = *(const half8*)(lA0 + aRd + i * 2048 + kg0);
      afE[i][1] = *(const half8*)(lA0 + aRd + i * 2048 + kg1);
    }
#pragma unroll
    for (int ni = 0; ni < N_REP; ++ni) {
      bf0[ni][0] = *(const half8*)(lB0 + bRd + ni * 2048 + kg0);
      bf0[ni][1] = *(const half8*)(lB0 + bRd + ni * 2048 + kg1);
    }
  }
#pragma unroll
  for (int j = 0; j < N_REP; ++j)
    gload16(bS + (long)(j * 64) * ldb + 64, ldsB + BSZ + j * 4096 + wv * 512);

  for (int tt = 0; tt < nt; tt += 2) {
    TILE(tt, 0, bf0, bf1)
    TILE(tt + 1, 1, bf1, bf0)
  }

  // epilogue: C/D layout col=lane&15, row=fq*4+reg
  const int row0 = bm + wr * 128 + fq * 4;
  const int col0 = bn + wc * (16 * N_REP) + fr;
#pragma unroll
  for (int mi = 0; mi < 8; ++mi) {
#pragma unroll
    for (int ni = 0; ni < N_REP; ++ni) {
      f32x4 c = acc[mi][ni];
      const long r0 = row0 + mi * 16;
      const long e  = col0 + ni * 16;
      if constexpr (MODE == 0) {
        _Float16* q  = (_Float16*)o0;
        _Float16* kk = (_Float16*)o1;
        _Float16* vv = (_Float16*)o2;
#pragma unroll
        for (int j = 0; j < 4; ++j) {
          const long i = r0 + j;
          const float val = c[j];
          if (e < 1024)      q [i * 1024 + e]          = (_Float16)(val * 0.03125f);
          else if (e < 2048) kk[i * 1024 + (e - 1024)] = (_Float16)val;
          else               vv[i * 1024 + (e - 2048)] = (_Float16)val;
        }
      } else if constexpr (MODE == 1) {
        float* C = (float*)o0 + (long)bz * 2048 * 2048;
#pragma unroll
        for (int j = 0; j < 4; ++j) C[(r0 + j) * 2048 + e] = c[j];
      } else {
        float* C = (float*)o0 + (long)bz * 2048 * 1024;
#pragma unroll
        for (int j = 0; j < 4; ++j) C[(r0 + j) * 1024 + e] = c[j];
      }
    }
  }
}

// ---------------- transpose v [b][n][d] -> vT [b][d][n] (fp16) ----------------
__global__ __launch_bounds__(256) void transpose_v(
    const unsigned short* __restrict__ v, unsigned short* __restrict__ vT) {
  __shared__ unsigned short t[64][72];  // +8 pad
  const long b = blockIdx.z;
  const unsigned short* vb = v + b * (2048L * 1024);
  unsigned short* ob = vT + b * (1024L * 2048);
  const int n0 = blockIdx.y * 64;
  const int d0 = blockIdx.x * 64;
  const int tid = threadIdx.x;
  const int r  = tid >> 2;
  const int c0 = (tid & 3) * 16;
  const unsigned short* src = vb + (long)(n0 + r) * 1024 + d0 + c0;
  *(ushort4*)&t[r][c0]      = *(const ushort4*)(src);
  *(ushort4*)&t[r][c0 + 4]  = *(const ushort4*)(src + 4);
  *(ushort4*)&t[r][c0 + 8]  = *(const ushort4*)(src + 8);
  *(ushort4*)&t[r][c0 + 12] = *(const ushort4*)(src + 12);
  __syncthreads();
  union { unsigned short h[8]; ushort8 u; } w0, w1;
#pragma unroll
  for (int j = 0; j < 8; ++j) w0.h[j] = t[c0 + j][r];
#pragma unroll
  for (int j = 0; j < 8; ++j) w1.h[j] = t[c0 + 8 + j][r];
  unsigned short* dst = ob + (long)(d0 + r) * 2048 + n0 + c0;
  *(ushort8*)dst       = w0.u;
  *(ushort8*)(dst + 8) = w1.u;
}

// ---------------- row softmax fp32[2048] -> fp16 in-place ----------------
__global__ __launch_bounds__(256) void softmax_rows(float* __restrict__ S) {
  const long row = blockIdx.x;
  float* p = S + row * 2048;
  const int t = threadIdx.x;
  float4 v0 = *(const float4*)(p + t * 8);
  float4 v1 = *(const float4*)(p + t * 8 + 4);
  float f[8] = {v0.x, v0.y, v0.z, v0.w, v1.x, v1.y, v1.z, v1.w};
  float m = f[0];
#pragma unroll
  for (int j = 1; j < 8; ++j) m = fmaxf(m, f[j]);
  for (int o = 32; o; o >>= 1) m = fmaxf(m, __shfl_xor(m, o));
  __shared__ float redm[4];
  if (!(t & 63)) redm[t >> 6] = m;
  __syncthreads();
  m = fmaxf(fmaxf(redm[0], redm[1]), fmaxf(redm[2], redm[3]));
  float e[8], s = 0.f;
#pragma unroll
  for (int j = 0; j < 8; ++j) { e[j] = __expf(f[j] - m); s += e[j]; }
  for (int o = 32; o; o >>= 1) s += __shfl_xor(s, o);
  __shared__ float reds[4];
  if (!(t & 63)) reds[t >> 6] = s;
  __syncthreads();
  s = reds[0] + reds[1] + reds[2] + reds[3];
  const float inv = 1.0f / s;
  union { _Float16 h[8]; ushort8 u; } r;
#pragma unroll
  for (int j = 0; j < 8; ++j) r.h[j] = (_Float16)(e[j] * inv);
  *(ushort8*)((unsigned short*)p + t * 8) = r.u;  // P fp16, row pitch 4096 halves
}

extern "C" void kernel_launch(void* const* d_in, const int* in_sizes, int n_in,
                              void* d_out, int out_size, void* d_ws, size_t ws_size,
                              hipStream_t stream) {
  const float* x = (const float*)d_in[0];   // [4,2048,1024]
  const float* W = (const float*)d_in[1];   // [3072,1024]
  float* out = (float*)d_out;               // [4,2048,1024] fp32
  char* ws = (char*)d_ws;

  const long MB16 = 16777216;  // 8192*1024*2 bytes
  unsigned short* q  = (unsigned short*)(ws);
  unsigned short* k  = (unsigned short*)(ws + MB16);
  unsigned short* vT = (unsigned short*)(ws + 2 * MB16);
  float*          S  = (float*)(ws + 3 * MB16);              // 64 MiB
  // aliased into S region (dead before S is written):
  unsigned short* xb = (unsigned short*)(ws + 3 * MB16);
  unsigned short* wb = (unsigned short*)(ws + 4 * MB16);
  unsigned short* v  = (unsigned short*)(ws + 4 * MB16 + 6291456);

  // 1. casts
  cast_f32_f16<<<4096, 256, 0, stream>>>(x, xb, 8388608L);
  cast_f32_f16<<<1536, 256, 0, stream>>>(W, wb, 3145728L);
  // 2. qkv = x @ W^T (M=8192, N=3072, K=1024), BM=256 BN=192 -> 512 blocks
  gemm8p<0, 3><<<dim3(16, 32, 1), 512, 0, stream>>>(
      xb, wb, 1024, 1024, 1024, 0L, 0L, q, k, v);
  // 3. v -> vT per batch
  transpose_v<<<dim3(16, 32, 4), 256, 0, stream>>>(v, vT);
  // 4. S = (q*scale) @ k^T per batch (M=N=2048, K=1024), BM=BN=256 -> 256 blocks
  gemm8p<1, 4><<<dim3(8, 8, 4), 512, 0, stream>>>(
      q, k, 1024, 1024, 1024, 2048L * 1024, 2048L * 1024, S, nullptr, nullptr);
  // 5. row softmax, P fp16 in place (row pitch 4096 halves)
  softmax_rows<<<8192, 256, 0, stream>>>(S);
  // 6. out = P @ vT^T per batch (M=2048, N=1024, K=2048), BM=256 BN=128 -> 256 blocks
  gemm8p<2, 2><<<dim3(8, 8, 4), 512, 0, stream>>>(
      (unsigned short*)S, vT, 2048, 4096, 2048, 2048L * 4096, 1024L * 2048,
      out, nullptr, nullptr);
}

// Round 5
// 172.130 us; speedup vs baseline: 1.2820x; 1.2820x over previous
//
#include <hip/hip_runtime.h>

using half8   = __attribute__((ext_vector_type(8))) _Float16;
using f32x4   = __attribute__((ext_vector_type(4))) float;
using ushort8 = __attribute__((ext_vector_type(8))) unsigned short;

__device__ __forceinline__ void gload16(const void* g, void* l) {
  __builtin_amdgcn_global_load_lds(
      (const __attribute__((address_space(1))) void*)g,
      (__attribute__((address_space(3))) void*)l, 16, 0, 0);
}

// XCD-aware bijective swizzle with 8x4 2D rects: 32 consecutive work-ids form
// an 8(x)-by-4(y) rect; each XCD's contiguous chunk (nwg/8, multiple of 32)
// walks whole rects -> the 32 co-resident blocks of one XCD share 4 A-panels +
// 8 B-panels (~4MB ~ per-XCD L2). Requires gx%8==0, gy%4==0, nwg%8==0.
__device__ __forceinline__ void xcd_swizzle(int& x, int& y, int& z) {
  const int gx = gridDim.x, gy = gridDim.y;
  const int nwg = gx * gy * gridDim.z;
  const int f = blockIdx.x + gx * (blockIdx.y + gy * blockIdx.z);
  const int w = (f & 7) * (nwg >> 3) + (f >> 3);
  const int r = w >> 5, u = w & 31;
  const int nrx = gx >> 3, nry = gy >> 2;
  const int pz  = nrx * nry;
  const int rz  = r / pz, rr = r % pz;
  x = (rr % nrx) * 8 + (u & 7);
  y = (rr / nrx) * 4 + (u >> 3);
  z = rz;
}

// ---------------- cast fp32 -> fp16 ----------------
__global__ __launch_bounds__(256) void cast_f32_f16(
    const float* __restrict__ in, unsigned short* __restrict__ out, long n) {
  long i = ((long)blockIdx.x * 256 + threadIdx.x) * 8;
  if (i >= n) return;
  float4 a = *(const float4*)(in + i);
  float4 b = *(const float4*)(in + i + 4);
  union { _Float16 h[8]; ushort8 u; } r;
  r.h[0] = (_Float16)a.x; r.h[1] = (_Float16)a.y;
  r.h[2] = (_Float16)a.z; r.h[3] = (_Float16)a.w;
  r.h[4] = (_Float16)b.x; r.h[5] = (_Float16)b.y;
  r.h[6] = (_Float16)b.z; r.h[7] = (_Float16)b.w;
  *(ushort8*)(out + i) = r.u;
}

// ============ 8-wave single-barrier-region NT GEMM: C = A[M,K]*B[N,K]^T ============
// BM=256, BN=64*N_REP, BK=64, 512 threads (2Mx4N waves), per-wave 128 x 16*N_REP.
// Region (t,p) = { s_barrier; lgkmcnt(0); 4*N_REP MFMA on frags read LAST region;
//                  stage-issues; ds_reads for NEXT region; [fence] }.
// Staging: A(t+1)[4] at p0 -> A slot^1; B(t+2)[N_REP] at p1 -> B slot cur (dead:
// consumed from regs). Producer fence vmcnt(N_REP) at END of p2, before the p3
// barrier after which waves read staged A(t+1)/B(t+1) -> cross-wave safe, never
// drains to 0 in steady state. B-frags double-buffered in regs; tile loop
// unrolled x2 for compile-time frag indices. N_REP<=3 to avoid spills
// (acc = 32*N_REP AGPR; frags ~(32+16*N_REP)*2 VGPR).
#define FENCE_N()                                                                  \
  do {                                                                             \
    if constexpr (N_REP == 2)      asm volatile("s_waitcnt vmcnt(2)" ::: "memory");\
    else if constexpr (N_REP == 3) asm volatile("s_waitcnt vmcnt(3)" ::: "memory");\
    else                           asm volatile("s_waitcnt vmcnt(4)" ::: "memory");\
  } while (0)

#define PHASE(P, AC, AN, BC, BNX)                                                  \
  {                                                                                \
    __builtin_amdgcn_s_barrier();                                                  \
    asm volatile("s_waitcnt lgkmcnt(0)" ::: "memory");                             \
    __builtin_amdgcn_sched_barrier(0);                                             \
    __builtin_amdgcn_s_setprio(1);                                                 \
    _Pragma("unroll") for (int ks = 0; ks < 2; ++ks)                               \
    _Pragma("unroll") for (int i = 0; i < 2; ++i)                                  \
    _Pragma("unroll") for (int ni = 0; ni < N_REP; ++ni)                           \
      acc[2 * (P) + i][ni] = __builtin_amdgcn_mfma_f32_16x16x32_f16(               \
          AC[i][ks], BC[ni][ks], acc[2 * (P) + i][ni], 0, 0, 0);                   \
    __builtin_amdgcn_s_setprio(0);                                                 \
    __builtin_amdgcn_sched_barrier(0);                                             \
    if ((P) == 0 && t + 1 < nt) {                                                  \
      unsigned short* d = ldsA + (SLOT ^ 1) * ASZ + wv * 512;                      \
      const long kt = (long)(t + 1) * 64;                                          \
      gload16(aS + kt, d);                                                         \
      gload16(aS + (long)64 * lda + kt, d + 4096);                                 \
      gload16(aS + (long)128 * lda + kt, d + 8192);                                \
      gload16(aS + (long)192 * lda + kt, d + 12288);                               \
    }                                                                              \
    if ((P) == 1 && t + 2 < nt) {                                                  \
      const long kt = (long)(t + 2) * 64;                                          \
      _Pragma("unroll") for (int j = 0; j < N_REP; ++j)                            \
        gload16(bS + (long)(j * 64) * ldb + kt,                                    \
                ldsB + SLOT * BSZ + j * 4096 + wv * 512);                          \
    }                                                                              \
    if ((P) < 3) {                                                                 \
      _Pragma("unroll") for (int i = 0; i < 2; ++i) {                              \
        AN[i][0] = *(const half8*)(lA + aRd + (2 * ((P) + 1) + i) * 2048 + kg0);   \
        AN[i][1] = *(const half8*)(lA + aRd + (2 * ((P) + 1) + i) * 2048 + kg1);   \
      }                                                                            \
    } else if (t + 1 < nt) {                                                       \
      _Pragma("unroll") for (int i = 0; i < 2; ++i) {                              \
        AN[i][0] = *(const half8*)(lAo + aRd + i * 2048 + kg0);                    \
        AN[i][1] = *(const half8*)(lAo + aRd + i * 2048 + kg1);                    \
      }                                                                            \
      _Pragma("unroll") for (int ni = 0; ni < N_REP; ++ni) {                       \
        BNX[ni][0] = *(const half8*)(lBo + bRd + ni * 2048 + kg0);                 \
        BNX[ni][1] = *(const half8*)(lBo + bRd + ni * 2048 + kg1);                 \
      }                                                                            \
    }                                                                              \
    if ((P) == 2) {                                                                \
      if (t + 2 < nt) FENCE_N();                                                   \
      else asm volatile("s_waitcnt vmcnt(0)" ::: "memory");                        \
    }                                                                              \
    __builtin_amdgcn_sched_barrier(0);                                             \
  }

#define TILE(T, S, BCARR, BNARR)                                                   \
  {                                                                                \
    const int t = (T);                                                             \
    constexpr int SLOT = (S);                                                      \
    const char* lA  = (const char*)(ldsA + SLOT * ASZ);                            \
    const char* lAo = (const char*)(ldsA + (SLOT ^ 1) * ASZ);                      \
    const char* lBo = (const char*)(ldsB + (SLOT ^ 1) * BSZ);                      \
    PHASE(0, afE, afO, BCARR, BNARR)                                               \
    PHASE(1, afO, afE, BCARR, BNARR)                                               \
    PHASE(2, afE, afO, BCARR, BNARR)                                               \
    PHASE(3, afO, afE, BCARR, BNARR)                                               \
  }

template <int MODE, int N_REP>
__global__ __launch_bounds__(512, 2) void gemm8p(
    const unsigned short* __restrict__ Ab, const unsigned short* __restrict__ Bb,
    int K, int lda, int ldb, long sA, long sB,
    void* __restrict__ o0, void* __restrict__ o1, void* __restrict__ o2) {
  constexpr int BM  = 256;
  constexpr int BN  = 64 * N_REP;
  constexpr int ASZ = BM * 64;
  constexpr int BSZ = BN * 64;
  __shared__ unsigned short lds[2 * ASZ + 2 * BSZ];

  const int tid  = threadIdx.x;
  const int lane = tid & 63;
  const int wv   = tid >> 6;
  const int wr   = wv >> 2, wc = wv & 3;
  const int fr   = lane & 15, fq = lane >> 4;
  int bxi, byi, bzi;
  xcd_swizzle(bxi, byi, bzi);
  const int bm = byi * BM;
  const int bn = bxi * BN;
  const int bz = bzi;

  const unsigned short* A = Ab + (long)bz * sA;
  const unsigned short* B = Bb + (long)bz * sB;

  // staging map: thread t -> row tid>>3 in a 64-row unit, 16B granule tid&7,
  // source pre-swizzled (gload_lds writes linearly; reads apply same XOR)
  const int row_s = tid >> 3;
  const int col_s = ((tid & 7) ^ (row_s & 7)) * 8;
  const unsigned short* aS = A + (long)(bm + row_s) * lda + col_s;
  const unsigned short* bS = B + (long)(bn + row_s) * ldb + col_s;
  unsigned short* ldsA = lds;
  unsigned short* ldsB = lds + 2 * ASZ;

  const int kg0 = ((0 * 4 + fq) ^ (fr & 7)) * 16;
  const int kg1 = ((1 * 4 + fq) ^ (fr & 7)) * 16;
  const int aRd = (wr * 128 + fr) * 128;
  const int bRd = (wc * (16 * N_REP) + fr) * 128;

  f32x4 acc[8][N_REP] = {};
  half8 afE[2][2], afO[2][2];
  half8 bf0[N_REP][2], bf1[N_REP][2];

  const int nt = K / 64;

  // ---- prologue: stage A(0),B(0); drain; read (0,p0) frags; issue B(1) ----
#pragma unroll
  for (int i = 0; i < 4; ++i)
    gload16(aS + (long)(i * 64) * lda, ldsA + i * 4096 + wv * 512);
#pragma unroll
  for (int j = 0; j < N_REP; ++j)
    gload16(bS + (long)(j * 64) * ldb, ldsB + j * 4096 + wv * 512);
  asm volatile("s_waitcnt vmcnt(0)" ::: "memory");
  __builtin_amdgcn_s_barrier();
  {
    const char* lA0 = (const char*)ldsA;
    const char* lB0 = (const char*)ldsB;
#pragma unroll
    for (int i = 0; i < 2; ++i) {
      afE[i][0] = *(const half8*)(lA0 + aRd + i * 2048 + kg0);
      afE[i][1] = *(const half8*)(lA0 + aRd + i * 2048 + kg1);
    }
#pragma unroll
    for (int ni = 0; ni < N_REP; ++ni) {
      bf0[ni][0] = *(const half8*)(lB0 + bRd + ni * 2048 + kg0);
      bf0[ni][1] = *(const half8*)(lB0 + bRd + ni * 2048 + kg1);
    }
  }
#pragma unroll
  for (int j = 0; j < N_REP; ++j)
    gload16(bS + (long)(j * 64) * ldb + 64, ldsB + BSZ + j * 4096 + wv * 512);

  for (int tt = 0; tt < nt; tt += 2) {
    TILE(tt, 0, bf0, bf1)
    TILE(tt + 1, 1, bf1, bf0)
  }

  // epilogue: C/D layout col=lane&15, row=fq*4+reg
  const int row0 = bm + wr * 128 + fq * 4;
  const int col0 = bn + wc * (16 * N_REP) + fr;
#pragma unroll
  for (int mi = 0; mi < 8; ++mi) {
#pragma unroll
    for (int ni = 0; ni < N_REP; ++ni) {
      f32x4 c = acc[mi][ni];
      const long r0 = row0 + mi * 16;
      const long e  = col0 + ni * 16;
      if constexpr (MODE == 0) {
        _Float16* q  = (_Float16*)o0;
        _Float16* kk = (_Float16*)o1;
        _Float16* vv = (_Float16*)o2;
#pragma unroll
        for (int j = 0; j < 4; ++j) {
          const long i = r0 + j;
          const float val = c[j];
          if (e < 1024)      q [i * 1024 + e]          = (_Float16)(val * 0.03125f);
          else if (e < 2048) kk[i * 1024 + (e - 1024)] = (_Float16)val;
          else               vv[i * 1024 + (e - 2048)] = (_Float16)val;
        }
      } else if constexpr (MODE == 1) {
        float* C = (float*)o0 + (long)bz * 2048 * 2048;
#pragma unroll
        for (int j = 0; j < 4; ++j) C[(r0 + j) * 2048 + e] = c[j];
      } else {
        float* C = (float*)o0 + (long)bz * 2048 * 1024;
#pragma unroll
        for (int j = 0; j < 4; ++j) C[(r0 + j) * 1024 + e] = c[j];
      }
    }
  }
}

// ---------------- transpose v [b][n][d] -> vT [b][d][n] (fp16) ----------------
__global__ __launch_bounds__(256) void transpose_v(
    const unsigned short* __restrict__ v, unsigned short* __restrict__ vT) {
  __shared__ unsigned short t[64][72];  // +8 pad
  const long b = blockIdx.z;
  const unsigned short* vb = v + b * (2048L * 1024);
  unsigned short* ob = vT + b * (1024L * 2048);
  const int n0 = blockIdx.y * 64;
  const int d0 = blockIdx.x * 64;
  const int tid = threadIdx.x;
  const int r  = tid >> 2;
  const int c0 = (tid & 3) * 16;
  const unsigned short* src = vb + (long)(n0 + r) * 1024 + d0 + c0;
  *(ushort4*)&t[r][c0]      = *(const ushort4*)(src);
  *(ushort4*)&t[r][c0 + 4]  = *(const ushort4*)(src + 4);
  *(ushort4*)&t[r][c0 + 8]  = *(const ushort4*)(src + 8);
  *(ushort4*)&t[r][c0 + 12] = *(const ushort4*)(src + 12);
  __syncthreads();
  union { unsigned short h[8]; ushort8 u; } w0, w1;
#pragma unroll
  for (int j = 0; j < 8; ++j) w0.h[j] = t[c0 + j][r];
#pragma unroll
  for (int j = 0; j < 8; ++j) w1.h[j] = t[c0 + 8 + j][r];
  unsigned short* dst = ob + (long)(d0 + r) * 2048 + n0 + c0;
  *(ushort8*)dst       = w0.u;
  *(ushort8*)(dst + 8) = w1.u;
}

// ---------------- row softmax fp32[2048] -> fp16 in-place ----------------
__global__ __launch_bounds__(256) void softmax_rows(float* __restrict__ S) {
  const long row = blockIdx.x;
  float* p = S + row * 2048;
  const int t = threadIdx.x;
  float4 v0 = *(const float4*)(p + t * 8);
  float4 v1 = *(const float4*)(p + t * 8 + 4);
  float f[8] = {v0.x, v0.y, v0.z, v0.w, v1.x, v1.y, v1.z, v1.w};
  float m = f[0];
#pragma unroll
  for (int j = 1; j < 8; ++j) m = fmaxf(m, f[j]);
  for (int o = 32; o; o >>= 1) m = fmaxf(m, __shfl_xor(m, o));
  __shared__ float redm[4];
  if (!(t & 63)) redm[t >> 6] = m;
  __syncthreads();
  m = fmaxf(fmaxf(redm[0], redm[1]), fmaxf(redm[2], redm[3]));
  float e[8], s = 0.f;
#pragma unroll
  for (int j = 0; j < 8; ++j) { e[j] = __expf(f[j] - m); s += e[j]; }
  for (int o = 32; o; o >>= 1) s += __shfl_xor(s, o);
  __shared__ float reds[4];
  if (!(t & 63)) reds[t >> 6] = s;
  __syncthreads();
  s = reds[0] + reds[1] + reds[2] + reds[3];
  const float inv = 1.0f / s;
  union { _Float16 h[8]; ushort8 u; } r;
#pragma unroll
  for (int j = 0; j < 8; ++j) r.h[j] = (_Float16)(e[j] * inv);
  *(ushort8*)((unsigned short*)p + t * 8) = r.u;  // P fp16, row pitch 4096 halves
}

extern "C" void kernel_launch(void* const* d_in, const int* in_sizes, int n_in,
                              void* d_out, int out_size, void* d_ws, size_t ws_size,
                              hipStream_t stream) {
  const float* x = (const float*)d_in[0];   // [4,2048,1024]
  const float* W = (const float*)d_in[1];   // [3072,1024]
  float* out = (float*)d_out;               // [4,2048,1024] fp32
  char* ws = (char*)d_ws;

  const long MB16 = 16777216;  // 8192*1024*2 bytes
  unsigned short* q  = (unsigned short*)(ws);
  unsigned short* k  = (unsigned short*)(ws + MB16);
  unsigned short* vT = (unsigned short*)(ws + 2 * MB16);
  float*          S  = (float*)(ws + 3 * MB16);              // 64 MiB
  // aliased into S region (dead before S is written):
  unsigned short* xb = (unsigned short*)(ws + 3 * MB16);
  unsigned short* wb = (unsigned short*)(ws + 4 * MB16);
  unsigned short* v  = (unsigned short*)(ws + 4 * MB16 + 6291456);

  // 1. casts
  cast_f32_f16<<<4096, 256, 0, stream>>>(x, xb, 8388608L);
  cast_f32_f16<<<1536, 256, 0, stream>>>(W, wb, 3145728L);
  // 2. qkv = x @ W^T (M=8192, N=3072, K=1024), BM=256 BN=192 -> 512 blocks
  gemm8p<0, 3><<<dim3(16, 32, 1), 512, 0, stream>>>(
      xb, wb, 1024, 1024, 1024, 0L, 0L, q, k, v);
  // 3. v -> vT per batch
  transpose_v<<<dim3(16, 32, 4), 256, 0, stream>>>(v, vT);
  // 4. S = (q*scale) @ k^T per batch (M=N=2048, K=1024), BM=256 BN=128 -> 512 blocks
  gemm8p<1, 2><<<dim3(16, 8, 4), 512, 0, stream>>>(
      q, k, 1024, 1024, 1024, 2048L * 1024, 2048L * 1024, S, nullptr, nullptr);
  // 5. row softmax, P fp16 in place (row pitch 4096 halves)
  softmax_rows<<<8192, 256, 0, stream>>>(S);
  // 6. out = P @ vT^T per batch (M=2048, N=1024, K=2048), BM=256 BN=128 -> 256 blocks
  gemm8p<2, 2><<<dim3(8, 8, 4), 512, 0, stream>>>(
      (unsigned short*)S, vT, 2048, 4096, 2048, 2048L * 4096, 1024L * 2048,
      out, nullptr, nullptr);
}